// Round 8
// baseline (206.525 us; speedup 1.0000x reference)
//
#include <hip/hip_runtime.h>
#include <cmath>

#define D_IN 1024
#define D_OUT 1024
#define NUM_HEADS 16
#define HEAD_DIM 64
#define BATCH 2
#define SEQ 2048
#define GK 1024
#define KT 32

typedef __attribute__((ext_vector_type(8))) short short8;
typedef __attribute__((ext_vector_type(4))) short short4v;
typedef __attribute__((ext_vector_type(4))) float float4v;

__device__ __forceinline__ unsigned short f2bf(float f) {
  unsigned int u = __builtin_bit_cast(unsigned int, f);
  unsigned int r = (u + 0x7FFFu + ((u >> 16) & 1u)) >> 16;
  return (unsigned short)r;
}
__device__ __forceinline__ float bf2f(unsigned short h) {
  return __builtin_bit_cast(float, (unsigned int)h << 16);
}

// async global->LDS, 16 B per lane. lds base must be wave-uniform.
__device__ __forceinline__ void async_copy16(void* lds, const void* g) {
  __builtin_amdgcn_global_load_lds(
      (const __attribute__((address_space(1))) unsigned int*)g,
      (__attribute__((address_space(3))) unsigned int*)lds, 16, 0, 0);
}

// ---------------------------------------------------------------------------
// Fused pre-pass. z<4: transpose W (fp32 [K][N] -> bf16 [N][K]);
// z==4: convert x fp32 -> bf16 (16 elems/thread).
// ---------------------------------------------------------------------------
__global__ __launch_bounds__(256) void prep(
    const float* __restrict__ x, const float* __restrict__ Wq,
    const float* __restrict__ Wk, const float* __restrict__ Wv,
    const float* __restrict__ Wo, unsigned short* __restrict__ xb,
    unsigned short* __restrict__ wqkv_t, unsigned short* __restrict__ wo_t) {
  const int z = blockIdx.z;
  if (z == 4) {
    const int bid = blockIdx.y * 32 + blockIdx.x;  // 0..1023
    const size_t i0 = ((size_t)bid * 256 + threadIdx.x) * 16;
#pragma unroll
    for (int half = 0; half < 2; ++half) {
      const size_t o = i0 + half * 8;
      float4 a = *(const float4*)(x + o);
      float4 b = *(const float4*)(x + o + 4);
      union { unsigned short u[8]; short8 v; } t;
      t.u[0] = f2bf(a.x); t.u[1] = f2bf(a.y); t.u[2] = f2bf(a.z); t.u[3] = f2bf(a.w);
      t.u[4] = f2bf(b.x); t.u[5] = f2bf(b.y); t.u[6] = f2bf(b.z); t.u[7] = f2bf(b.w);
      *(short8*)(xb + o) = t.v;
    }
    return;
  }
  const float* W = (z == 0) ? Wq : (z == 1) ? Wk : (z == 2) ? Wv : Wo;
  unsigned short* out = (z < 3) ? (wqkv_t + (size_t)z * 1024 * 1024) : wo_t;

  __shared__ float T[32][33];
  const int r = threadIdx.x >> 3;
  const int c4 = (threadIdx.x & 7) << 2;
  const int k0 = blockIdx.x * 32, n0 = blockIdx.y * 32;

  float4 v = *(const float4*)(W + (size_t)(k0 + r) * 1024 + n0 + c4);
  T[r][c4 + 0] = v.x; T[r][c4 + 1] = v.y; T[r][c4 + 2] = v.z; T[r][c4 + 3] = v.w;
  __syncthreads();

  union { unsigned short u[4]; short4v v4; } o;
#pragma unroll
  for (int i = 0; i < 4; ++i) o.u[i] = f2bf(T[c4 + i][r]);
  *(short4v*)(out + (size_t)(n0 + r) * 1024 + k0 + c4) = o.v4;
}

// ---------------------------------------------------------------------------
// bf16 MFMA GEMM core, BMI x 128 x 64 tile, XOR-swizzled LDS staging (0 bank
// conflicts, r6). BMI = 128 (4-wave 64x64 sub-tiles) or 64 (32x64).
// ---------------------------------------------------------------------------
template <int BMI>
__device__ __forceinline__ void gemm_core(
    const unsigned short* __restrict__ A, const unsigned short* __restrict__ Bt,
    unsigned short* As, unsigned short* Bs, int bm, int bn,
    float4v (&acc)[BMI / 32][4]) {
  constexpr int MI = BMI / 32;
  const int tid = threadIdx.x;
  const int wave = tid >> 6, lane = tid & 63;
  const int quad = lane >> 4, l16 = lane & 15;
  const int wr = wave >> 1, wc = wave & 1;
  const int sw = l16 & 7;

  int srowA[MI], sgcA[MI];
#pragma unroll
  for (int t = 0; t < MI; ++t) {
    const int c = (wave * MI + t) * 64 + lane;
    srowA[t] = c >> 3;
    sgcA[t] = ((c & 7) ^ (srowA[t] & 7)) * 8;
  }
  int srowB[4], sgcB[4];
#pragma unroll
  for (int t = 0; t < 4; ++t) {
    const int c = (wave * 4 + t) * 64 + lane;
    srowB[t] = c >> 3;
    sgcB[t] = ((c & 7) ^ (srowB[t] & 7)) * 8;
  }

  for (int k0 = 0; k0 < GK; k0 += 64) {
    __syncthreads();
#pragma unroll
    for (int t = 0; t < MI; ++t) {
      const int c = (wave * MI + t) * 64 + lane;
      async_copy16(As + (size_t)c * 8, A + (size_t)(bm + srowA[t]) * GK + k0 + sgcA[t]);
    }
#pragma unroll
    for (int t = 0; t < 4; ++t) {
      const int c = (wave * 4 + t) * 64 + lane;
      async_copy16(Bs + (size_t)c * 8, Bt + (size_t)(bn + srowB[t]) * GK + k0 + sgcB[t]);
    }
    __syncthreads();

#pragma unroll
    for (int h = 0; h < 2; ++h) {
      short8 af[MI], bf[4];
#pragma unroll
      for (int i = 0; i < MI; ++i) {
        const int row = wr * (BMI / 2) + i * 16 + l16;
        af[i] = *(const short8*)&As[((size_t)row * 8 + ((h * 4 + quad) ^ sw)) * 8];
      }
#pragma unroll
      for (int j = 0; j < 4; ++j) {
        const int row = wc * 64 + j * 16 + l16;
        bf[j] = *(const short8*)&Bs[((size_t)row * 8 + ((h * 4 + quad) ^ sw)) * 8];
      }
#pragma unroll
      for (int i = 0; i < MI; ++i)
#pragma unroll
        for (int j = 0; j < 4; ++j)
          acc[i][j] = __builtin_amdgcn_mfma_f32_16x16x32_bf16(af[i], bf[j], acc[i][j], 0, 0, 0);
    }
  }
}

// QKV GEMM: N = 3072 (Wq|Wk|Wv). Q pre-scaled by 0.125*log2(e), bhsd.
// K -> fragment-blocked kblk; V -> fragment-blocked vblk.
__global__ __launch_bounds__(256) void gemm_qkv(
    const unsigned short* __restrict__ A, const unsigned short* __restrict__ Bt,
    const float* __restrict__ bq, const float* __restrict__ bk,
    const float* __restrict__ bv,
    unsigned short* __restrict__ qbuf, unsigned short* __restrict__ kblk,
    unsigned short* __restrict__ vblk) {
  __shared__ unsigned short As[128 * 64];
  __shared__ unsigned short Bs[128 * 64];
  const int wave = threadIdx.x >> 6, lane = threadIdx.x & 63;
  const int quad = lane >> 4, l16 = lane & 15;
  const int wr = wave >> 1, wc = wave & 1;
  const int bm = blockIdx.x * 128, bn = blockIdx.y * 128;

  float4v acc[4][4] = {};
  gemm_core<128>(A, Bt, As, Bs, bm, bn, acc);

#pragma unroll
  for (int j = 0; j < 4; ++j) {
    const int n = bn + wc * 64 + j * 16 + l16;
    const int seg = n >> 10, nn = n & 1023;
    const int h = nn >> 6, d = nn & 63;
    const float bsv = (seg == 0) ? bq[nn] : (seg == 1) ? bk[nn] : bv[nn];
    const float scale = (seg == 0) ? 0.18033688011112043f : 1.0f;  // 0.125*log2e
#pragma unroll
    for (int i = 0; i < 4; ++i) {
#pragma unroll
      for (int r = 0; r < 4; ++r) {
        const int m = bm + wr * 64 + i * 16 + quad * 4 + r;
        const int b = m >> 11, s = m & 2047;
        const int bh = b * NUM_HEADS + h;
        const unsigned short hv = f2bf((acc[i][j][r] + bsv) * scale);
        if (seg == 0) {
          qbuf[((size_t)bh * SEQ + s) * HEAD_DIM + d] = hv;
        } else if (seg == 1) {
          kblk[((size_t)bh * 64 + (s >> 5)) * 2048 +
               (size_t)(((((s >> 4) & 1) * 2 + (d >> 5)) * 64 +
                         ((d >> 3) & 3) * 16 + (s & 15)) * 8 + (d & 7))] = hv;
        } else {
          vblk[((size_t)bh * 64 + (s >> 5)) * 2048 +
               (size_t)(((d >> 4) * 64 + ((s >> 3) & 3) * 16 + (d & 15)) * 8 +
                        (s & 7))] = hv;
        }
      }
    }
  }
}

// Output GEMM: N = 1024, fp32 out + bias. 64x128 tiles -> 512 blocks (2/CU).
__global__ __launch_bounds__(256) void gemm_out(
    const unsigned short* __restrict__ A, const unsigned short* __restrict__ Bt,
    const float* __restrict__ bo, float* __restrict__ out) {
  __shared__ unsigned short As[64 * 64];
  __shared__ unsigned short Bs[128 * 64];
  const int wave = threadIdx.x >> 6, lane = threadIdx.x & 63;
  const int quad = lane >> 4, l16 = lane & 15;
  const int wr = wave >> 1, wc = wave & 1;
  const int bm = blockIdx.x * 64, bn = blockIdx.y * 128;

  float4v acc[2][4] = {};
  gemm_core<64>(A, Bt, As, Bs, bm, bn, acc);

#pragma unroll
  for (int j = 0; j < 4; ++j) {
    const int n = bn + wc * 64 + j * 16 + l16;
    const float bsv = bo[n];
#pragma unroll
    for (int i = 0; i < 2; ++i) {
#pragma unroll
      for (int r = 0; r < 4; ++r) {
        const int m = bm + wr * 32 + i * 16 + quad * 4 + r;
        out[(size_t)m * D_OUT + n] = acc[i][j][r] + bsv;
      }
    }
  }
}

// ---------------------------------------------------------------------------
// Flash attention, in-block split-K-4, software-pipelined P round-trip.
// Per 32-key step: QK(t) MFMAs -> PV(t-1) MFMAs (P read in flight since last
// step) -> prefetch K(t+1)/V(t) (single register buffer, L2-resident) ->
// exp2+P-write -> issue ds_read P(t). l comes from a ones-column MFMA.
// End-of-kernel in-LDS combine across the 4 waves.
// ---------------------------------------------------------------------------
#define OBS 72

__global__ __launch_bounds__(256) void attn_kernel(
    const unsigned short* __restrict__ qf, const unsigned short* __restrict__ kblk,
    const unsigned short* __restrict__ vblk, unsigned short* __restrict__ ctx) {
  __shared__ unsigned short PL[4 * 2 * 32 * 40];  // per-wave double-buffered P (20 KB)
  __shared__ unsigned short OB[4 * 32 * OBS];     // per-wave partial O (18 KB)
  __shared__ float LL[4 * 32];                    // per-wave partial l

  const int id = blockIdx.x;
  const int bh = id & 31;                 // low bits -> XCD spread
  const int qblk = 63 - (id >> 5);        // long q-blocks first
  const int qw0 = qblk * 32;
  const int tid = threadIdx.x;
  const int w = tid >> 6;
  const int lane = tid & 63;
  const int quad = lane >> 4;
  const int l16 = lane & 15;

  const int nt = qblk + 1;                // total key tiles
  const int qch = (nt + 3) >> 2;
  const int t0 = w * qch;
  const int t1 = min(nt, t0 + qch);

  const size_t bh_base = (size_t)bh * SEQ * HEAD_DIM;
  const unsigned short* kb = kblk + bh_base;
  const unsigned short* vb = vblk + bh_base;

  short8 aq[2][2];
#pragma unroll
  for (int qt = 0; qt < 2; ++qt) {
    const unsigned short* qrow =
        qf + bh_base + (size_t)(qw0 + qt * 16 + l16) * HEAD_DIM + quad * 8;
    aq[qt][0] = *(const short8*)qrow;
    aq[qt][1] = *(const short8*)(qrow + 32);
  }

  float4v O[2][4] = {};
  float4v Ol[2] = {};
  short8 pPrev[2];

  union { unsigned short u[8]; short8 v; } onesu;
#pragma unroll
  for (int i = 0; i < 8; ++i) onesu.u[i] = 0x3F80;  // bf16 1.0
  const short8 onesf = onesu.v;

  unsigned short* PLw = PL + w * (2 * 32 * 40);

  if (t0 < t1) {
    short8 kf[4], vf[4];

    auto loadK = [&](int kt) {
      const size_t base = (size_t)kt * 2048 + lane * 8;
#pragma unroll
      for (int f = 0; f < 4; ++f) kf[f] = *(const short8*)(kb + base + f * 512);
    };
    auto loadV = [&](int kt) {
      const size_t base = (size_t)kt * 2048 + lane * 8;
#pragma unroll
      for (int f = 0; f < 4; ++f) vf[f] = *(const short8*)(vb + base + f * 512);
    };

    loadK(t0);
    for (int kt = t0; kt < t1; ++kt) {
      // ---- QK^T for tile kt ----
      float4v cs[2][2];
#pragma unroll
      for (int qt = 0; qt < 2; ++qt)
#pragma unroll
        for (int g = 0; g < 2; ++g) {
          float4v c = {0.f, 0.f, 0.f, 0.f};
          c = __builtin_amdgcn_mfma_f32_16x16x32_bf16(aq[qt][0], kf[2 * g], c, 0, 0, 0);
          c = __builtin_amdgcn_mfma_f32_16x16x32_bf16(aq[qt][1], kf[2 * g + 1], c, 0, 0, 0);
          cs[qt][g] = c;
        }

      // ---- PV for tile kt-1 (P frags in flight since last step) ----
      if (kt > t0) {
#pragma unroll
        for (int qt = 0; qt < 2; ++qt) {
#pragma unroll
          for (int jj = 0; jj < 4; ++jj)
            O[qt][jj] = __builtin_amdgcn_mfma_f32_16x16x32_bf16(pPrev[qt], vf[jj], O[qt][jj], 0, 0, 0);
          Ol[qt] = __builtin_amdgcn_mfma_f32_16x16x32_bf16(pPrev[qt], onesf, Ol[qt], 0, 0, 0);
        }
      }

      // ---- prefetch (single buffers; vf(kt-1) consumed above) ----
      if (kt + 1 < t1) loadK(kt + 1);
      loadV(kt);

      // ---- softmax (fixed-max exp2) + P write ----
      unsigned short* PLp = PLw + (kt & 1) * (32 * 40);
      const bool masked = (kt == nt - 1);
      const int k0 = kt * KT;
#pragma unroll
      for (int qt = 0; qt < 2; ++qt)
#pragma unroll
        for (int g = 0; g < 2; ++g)
#pragma unroll
          for (int r = 0; r < 4; ++r) {
            float s = cs[qt][g][r];
            if (masked) {
              const int key = k0 + g * 16 + l16;
              const int qg = qw0 + qt * 16 + quad * 4 + r;
              s = (key <= qg) ? s : -1e30f;
            }
            const float p = __builtin_exp2f(s);
            const unsigned int pu = __builtin_bit_cast(unsigned int, p);
            PLp[(qt * 16 + quad * 4 + r) * 40 + (g * 2 + (l16 >> 3)) * 8 + (l16 & 7)] =
                (unsigned short)(pu >> 16);
          }

      // ---- issue P A-frag reads (consumed next iteration) ----
#pragma unroll
      for (int qt = 0; qt < 2; ++qt)
        pPrev[qt] = *(const short8*)&PLp[(qt * 16 + l16) * 40 + quad * 8];
    }

    // ---- final PV for tile t1-1 ----
#pragma unroll
    for (int qt = 0; qt < 2; ++qt) {
#pragma unroll
      for (int jj = 0; jj < 4; ++jj)
        O[qt][jj] = __builtin_amdgcn_mfma_f32_16x16x32_bf16(pPrev[qt], vf[jj], O[qt][jj], 0, 0, 0);
      Ol[qt] = __builtin_amdgcn_mfma_f32_16x16x32_bf16(pPrev[qt], onesf, Ol[qt], 0, 0, 0);
    }
  }

  // ---- write this wave's partials to LDS ----
#pragma unroll
  for (int qt = 0; qt < 2; ++qt)
#pragma unroll
    for (int r = 0; r < 4; ++r) {
      const int row = qt * 16 + quad * 4 + r;
      if (l16 == 0) LL[w * 32 + row] = Ol[qt][r];
#pragma unroll
      for (int jj = 0; jj < 4; ++jj)
        OB[(w * 32 + row) * OBS + jj * 16 + l16] = f2bf(O[qt][jj][r]);
    }

  __syncthreads();

  // ---- in-LDS combine: wave w handles rows w*8..w*8+7 ----
  const int row = w * 8 + (lane >> 3);
  const int col0 = (lane & 7) * 8;
  float acc[8] = {};
#pragma unroll
  for (int u = 0; u < 4; ++u) {
    const short8 t = *(const short8*)&OB[(u * 32 + row) * OBS + col0];
#pragma unroll
    for (int i = 0; i < 8; ++i) acc[i] += bf2f((unsigned short)t[i]);
  }
  const float inv = 1.0f / (LL[row] + LL[32 + row] + LL[64 + row] + LL[96 + row]);
  union { unsigned short u[8]; short8 v; } o;
#pragma unroll
  for (int i = 0; i < 8; ++i) o.u[i] = f2bf(acc[i] * inv);
  const int b = bh >> 4, h = bh & 15;
  const int qg = qw0 + row;
  *(short8*)(ctx + ((size_t)b * SEQ + qg) * D_OUT + h * HEAD_DIM + col0) = o.v;
}

// ---------------------------------------------------------------------------
extern "C" void kernel_launch(void* const* d_in, const int* in_sizes, int n_in,
                              void* d_out, int out_size, void* d_ws, size_t ws_size,
                              hipStream_t stream) {
  const float* x  = (const float*)d_in[0];
  const float* Wq = (const float*)d_in[1];
  const float* bq = (const float*)d_in[2];
  const float* Wk = (const float*)d_in[3];
  const float* bk = (const float*)d_in[4];
  const float* Wv = (const float*)d_in[5];
  const float* bv = (const float*)d_in[6];
  const float* Wo = (const float*)d_in[7];
  const float* bo = (const float*)d_in[8];
  float* out = (float*)d_out;

  const int M = BATCH * SEQ;  // 4096
  unsigned short* xb     = (unsigned short*)d_ws;                  // 8 MB
  unsigned short* wqkv_t = xb + (size_t)M * D_IN;                  // 6 MB
  unsigned short* wo_t   = wqkv_t + (size_t)3 * D_OUT * D_IN;      // 2 MB
  unsigned short* qb     = wo_t + (size_t)D_OUT * D_OUT;           // 8 MB
  unsigned short* kblk   = qb + (size_t)M * D_OUT;                 // 8 MB
  unsigned short* vblk   = kblk + (size_t)M * D_OUT;               // 8 MB
  unsigned short* cb     = vblk + (size_t)M * D_OUT;               // 8 MB

  prep<<<dim3(32, 32, 5), 256, 0, stream>>>(x, Wq, Wk, Wv, Wo, xb, wqkv_t, wo_t);
  gemm_qkv<<<dim3(M / 128, 3 * D_OUT / 128), 256, 0, stream>>>(
      xb, wqkv_t, bq, bk, bv, qb, kblk, vblk);
  attn_kernel<<<dim3(32 * 64), 256, 0, stream>>>(qb, kblk, vblk, cb);
  gemm_out<<<dim3(M / 64, D_OUT / 128), 256, 0, stream>>>(cb, wo_t, bo, out);
}